// Round 16
// baseline (1133.416 us; speedup 1.0000x reference)
//
#include <hip/hip_runtime.h>

// ---------------------------------------------------------------------------
// Transformer (B=2, N=2048, D=1024, H=16, DH=64, DEPTH=4, FF=4, GEGLU, causal)
// R16: attention pair-loop barriers fully counted — raw s_barrier after the
// two computes (ds_reads already drained by MFMA deps), then stage pair,
// then vmcnt(4)+s_barrier join (never a full drain in steady state).
// GEMMs (gemm4, R11 config) and everything else unchanged from R15.
// ---------------------------------------------------------------------------

typedef float f32x4 __attribute__((ext_vector_type(4)));
typedef __bf16 bf16x8 __attribute__((ext_vector_type(8)));
typedef unsigned short u16;
typedef unsigned int u32;

#define SCALE2 0.18033688011112042f   // DH^-0.5 * log2(e)
#define LN_EPS 1e-3f
#define DEFER_THR 8.0f                // log2-domain: P bounded by 2^8

__device__ __forceinline__ float fexp2(float x) { return __builtin_amdgcn_exp2f(x); }

__device__ __forceinline__ u16 f2bf(float f) {
  u32 u = __float_as_uint(f);
  u += 0x7fffu + ((u >> 16) & 1u);   // round-to-nearest-even
  return (u16)(u >> 16);
}

// async global->LDS, 16B/lane; lds base wave-uniform (HW adds lane*16)
__device__ __forceinline__ void stage16(void* lds_wave_base, const void* gsrc) {
  __builtin_amdgcn_global_load_lds((__attribute__((address_space(1))) void*)gsrc,
                                   (__attribute__((address_space(3))) void*)lds_wave_base,
                                   16, 0, 0);
}

// ---------------------------------------------------------------------------
// Weight transpose + cast: W f32 [L][K][N] -> WT bf16 [L][N][K].
// permMode=1 (W1): rows permuted so 16 a-cols / 16 gate-cols alternate.
// ---------------------------------------------------------------------------
__global__ void wtrans_kernel(const float* __restrict__ W, u16* __restrict__ WT,
                              int K, int N, int permMode) {
  __shared__ float tile[32][33];
  const int n0 = blockIdx.x * 32, k0 = blockIdx.y * 32;
  const float* Wl = W + (size_t)blockIdx.z * K * N;
  u16* WTl = WT + (size_t)blockIdx.z * K * N;
  const int tx = threadIdx.x, ty = threadIdx.y;
#pragma unroll
  for (int i = 0; i < 4; ++i)
    tile[ty + i * 8][tx] = Wl[(size_t)(k0 + ty + i * 8) * N + n0 + tx];
  __syncthreads();
#pragma unroll
  for (int i = 0; i < 4; ++i) {
    const int n = n0 + ty + i * 8;
    int orow;
    if (permMode) {
      orow = (n < 4096) ? (((n >> 4) << 5) + (n & 15))
                        : ((((n - 4096) >> 4) << 5) + 16 + (n & 15));
    } else {
      orow = n;
    }
    WTl[(size_t)orow * K + k0 + tx] = f2bf(tile[tx][ty + i * 8]);
  }
}

// V part of qkv -> per-(b,h) transposed V^T [bh][64 d][2048 tok] (bf16)
__global__ void vtrans_kernel(const u16* __restrict__ qkv, u16* __restrict__ Vt) {
  __shared__ u16 tile[32][33];
  const int t0 = blockIdx.x * 32, d0 = blockIdx.y * 32, bh = blockIdx.z;
  const int b = bh >> 4, h = bh & 15;
  const int tx = threadIdx.x, ty = threadIdx.y;
#pragma unroll
  for (int i = 0; i < 4; ++i)
    tile[ty + i * 8][tx] =
        qkv[((size_t)(b * 2048 + t0 + ty + i * 8)) * 3072 + 2048 + h * 64 + d0 + tx];
  __syncthreads();
#pragma unroll
  for (int i = 0; i < 4; ++i)
    Vt[((size_t)bh * 64 + d0 + ty + i * 8) * 2048 + t0 + tx] = tile[tx][ty + i * 8];
}

// ---------------------------------------------------------------------------
// LayerNorm: x f32 [4096][1024] -> y bf16
// ---------------------------------------------------------------------------
__global__ __launch_bounds__(256, 4)
void ln_kernel(const float* __restrict__ x, const float* __restrict__ g,
               const float* __restrict__ b, u16* __restrict__ y) {
  const int row = blockIdx.x, tid = threadIdx.x;
  const float4 v = ((const float4*)(x + (size_t)row * 1024))[tid];
  float s = v.x + v.y + v.z + v.w;
  float s2 = v.x * v.x + v.y * v.y + v.z * v.z + v.w * v.w;
#pragma unroll
  for (int off = 32; off > 0; off >>= 1) {
    s += __shfl_down(s, off);
    s2 += __shfl_down(s2, off);
  }
  __shared__ float ps[8];
  __shared__ float stats[2];
  const int wv = tid >> 6, lane = tid & 63;
  if (lane == 0) { ps[wv] = s; ps[wv + 4] = s2; }
  __syncthreads();
  if (tid == 0) {
    const float S = ps[0] + ps[1] + ps[2] + ps[3];
    const float S2 = ps[4] + ps[5] + ps[6] + ps[7];
    const float mu = S * (1.0f / 1024.0f);
    const float var = S2 * (1.0f / 1024.0f) - mu * mu;
    stats[0] = mu;
    stats[1] = rsqrtf(var + LN_EPS);
  }
  __syncthreads();
  const float mu = stats[0], rs = stats[1];
  const float4 gg = ((const float4*)g)[tid];
  const float4 bb = ((const float4*)b)[tid];
  ushort4 ov;
  ov.x = f2bf((v.x - mu) * rs * gg.x + bb.x);
  ov.y = f2bf((v.y - mu) * rs * gg.y + bb.y);
  ov.z = f2bf((v.z - mu) * rs * gg.z + bb.z);
  ov.w = f2bf((v.w - mu) * rs * gg.w + bb.w);
  ((ushort4*)(y + (size_t)row * 1024))[tid] = ov;
}

// ---------------------------------------------------------------------------
// gemm4 (R11, unchanged): BK=64 cross-tile ks-split pipeline, 2 LDS buffers,
// XOR-swizzled 128B rows, counted vmcnt joins, setprio MFMA clusters.
// ---------------------------------------------------------------------------
template <int EPI, int BM, int BN, int WM, int WN>
__global__ __launch_bounds__(WM * WN * 64, 2)
void gemm4(const u16* __restrict__ A, const u16* __restrict__ B,
           float* __restrict__ resid, const float* __restrict__ bias,
           u16* __restrict__ out, int M, int N, int K) {
  constexpr int NTHR = WM * WN * 64;
  constexpr int MT = BM / WM / 16;
  constexpr int NT = BN / WN / 16;
  __shared__ __align__(16) u16 lds[2][(BM + BN) * 64];

  const int tid = threadIdx.x;
  const int wv = tid >> 6, lane = tid & 63;
  const int lr = lane & 15, lg = lane >> 4;
  const int wmi = wv / WN, wni = wv % WN;
  const int RB0 = wmi * (BM / WM), CB0 = wni * (BN / WN);

  const int nwg = (int)(gridDim.x * gridDim.y);
  int id = (int)(blockIdx.y * gridDim.x + blockIdx.x);
  id = (id & 7) * (nwg >> 3) + (id >> 3);
  const int m0 = (id / (int)gridDim.x) * BM, n0 = (id % (int)gridDim.x) * BN;

  auto stage = [&](int bsel, int k0) {
    u16* dstA = &lds[bsel][0];
    u16* dstB = &lds[bsel][BM * 64];
#pragma unroll
    for (int rnd = 0; rnd < (BM * 128) / (NTHR * 16); ++rnd) {
      const int base = rnd * (NTHR * 16) + wv * 1024;
      const int off = base + lane * 16;
      const int row = off >> 7;
      const int k2 = (off & 127) ^ ((row & 7) << 4);
      stage16((char*)dstA + base, A + (size_t)(m0 + row) * K + k0 + (k2 >> 1));
    }
#pragma unroll
    for (int rnd = 0; rnd < (BN * 128) / (NTHR * 16); ++rnd) {
      const int base = rnd * (NTHR * 16) + wv * 1024;
      const int off = base + lane * 16;
      const int row = off >> 7;
      const int k2 = (off & 127) ^ ((row & 7) << 4);
      stage16((char*)dstB + base, B + (size_t)(n0 + row) * K + k0 + (k2 >> 1));
    }
  };

  f32x4 acc[MT][NT] = {};
  bf16x8 afr0[MT], bfr0[NT], afr1[MT], bfr1[NT];

  auto rd = [&](int bsel, int ks, bf16x8 (&af)[MT], bf16x8 (&bf)[NT]) {
    const char* As = (const char*)&lds[bsel][0];
    const char* Bs = (const char*)&lds[bsel][BM * 64];
#pragma unroll
    for (int mt = 0; mt < MT; ++mt) {
      const int row = RB0 + mt * 16 + lr;
      af[mt] = *(const bf16x8*)(As + row * 128 + ((ks * 64 + lg * 16) ^ ((lr & 7) << 4)));
    }
#pragma unroll
    for (int nt = 0; nt < NT; ++nt) {
      const int row = CB0 + nt * 16 + lr;
      bf[nt] = *(const bf16x8*)(Bs + row * 128 + ((ks * 64 + lg * 16) ^ ((lr & 7) << 4)));
    }
  };

  const int nT = K >> 6;
  stage(0, 0);
  stage(1, 64);
  asm volatile("s_waitcnt vmcnt(8)\n\ts_barrier" ::: "memory");
  rd(0, 0, afr0, bfr0);
  __builtin_amdgcn_sched_barrier(0);

  for (int t = 0; t < nT; ++t) {
    const int c = t & 1;
    rd(c, 1, afr1, bfr1);
    __builtin_amdgcn_sched_barrier(0);
    __builtin_amdgcn_s_setprio(1);
#pragma unroll
    for (int mt = 0; mt < MT; ++mt)
#pragma unroll
      for (int nt = 0; nt < NT; ++nt)
        acc[mt][nt] = __builtin_amdgcn_mfma_f32_16x16x32_bf16(
            afr0[mt], bfr0[nt], acc[mt][nt], 0, 0, 0);
    __builtin_amdgcn_s_setprio(0);
    __builtin_amdgcn_sched_barrier(0);
    asm volatile("s_waitcnt lgkmcnt(0)\n\ts_barrier" ::: "memory");
    __builtin_amdgcn_sched_barrier(0);
    if (t + 2 < nT) stage(c, (t + 2) * 64);
    if (t + 1 < nT) {
      if (t + 2 < nT)
        asm volatile("s_waitcnt vmcnt(8)\n\ts_barrier" ::: "memory");
      else
        asm volatile("s_waitcnt vmcnt(0)\n\ts_barrier" ::: "memory");
      rd(c ^ 1, 0, afr0, bfr0);
      __builtin_amdgcn_sched_barrier(0);
    }
    __builtin_amdgcn_s_setprio(1);
#pragma unroll
    for (int mt = 0; mt < MT; ++mt)
#pragma unroll
      for (int nt = 0; nt < NT; ++nt)
        acc[mt][nt] = __builtin_amdgcn_mfma_f32_16x16x32_bf16(
            afr1[mt], bfr1[nt], acc[mt][nt], 0, 0, 0);
    __builtin_amdgcn_s_setprio(0);
  }

  // C/D: m = m0 + RB0 + mt*16 + lg*4 + r ; n = n0 + CB0 + nt*16 + lr
  if (EPI == 0) {
#pragma unroll
    for (int mt = 0; mt < MT; ++mt)
#pragma unroll
      for (int nt = 0; nt < NT; ++nt) {
        const int n = n0 + CB0 + nt * 16 + lr;
#pragma unroll
        for (int r = 0; r < 4; ++r) {
          const int m = m0 + RB0 + mt * 16 + lg * 4 + r;
          out[(size_t)m * N + n] = f2bf(acc[mt][nt][r]);
        }
      }
  } else if (EPI == 1) {
    float bs[NT];
#pragma unroll
    for (int nt = 0; nt < NT; ++nt) bs[nt] = bias[n0 + CB0 + nt * 16 + lr];
#pragma unroll
    for (int mt = 0; mt < MT; ++mt)
#pragma unroll
      for (int nt = 0; nt < NT; ++nt) {
        const int n = n0 + CB0 + nt * 16 + lr;
#pragma unroll
        for (int r = 0; r < 4; ++r) {
          const int m = m0 + RB0 + mt * 16 + lg * 4 + r;
          resid[(size_t)m * N + n] += acc[mt][nt][r] + bs[nt];
        }
      }
  } else {
#pragma unroll
    for (int pt = 0; pt < NT / 2; ++pt) {
      const int colA = ((n0 + CB0 + pt * 32) >> 5) * 16 + lr;
      const float ba = bias[colA];
      const float bg = bias[4096 + colA];
#pragma unroll
      for (int mt = 0; mt < MT; ++mt)
#pragma unroll
        for (int r = 0; r < 4; ++r) {
          const int m = m0 + RB0 + mt * 16 + lg * 4 + r;
          const float a = acc[mt][2 * pt][r] + ba;
          const float g = acc[mt][2 * pt + 1][r] + bg;
          const float gl = 0.5f * g * (1.0f + erff(g * 0.70710678118654752f));
          out[(size_t)m * 4096 + colA] = f2bf(a * gl);
        }
    }
  }
}

// ---------------------------------------------------------------------------
// Causal flash attention, quad-buffered K/V, counted 2-K-tile barrier pairs:
//   compute kt, kt+1  -> raw s_barrier (ds_reads already drained via MFMA
//   deps; frees bufs kt,kt+1) -> stage kt+4,kt+5 -> vmcnt(4)+s_barrier
//   (forces kt+2,kt+3 landed; 4 newest loads stay in flight).
// 8-wave paired blocks, XCD-pinned bh, swapped QK^T, defer-max, per-lane l.
// ---------------------------------------------------------------------------
__global__ __launch_bounds__(512, 4)
void attn_kernel(const u16* __restrict__ qkv, const u16* __restrict__ Vt,
                 u16* __restrict__ attnout) {
  __shared__ __align__(16) u16 KV[4][2][64 * 64];   // 4 bufs x (K,V) = 64 KB
  __shared__ __align__(16) u16 Ps[8][16 * 64];      // wave-private P, 16 KB

  const int tid = threadIdx.x;
  const int wv = tid >> 6, lane = tid & 63;
  const int lr = lane & 15, lg = lane >> 4;
  const int lin = (int)(blockIdx.y * gridDim.x + blockIdx.x);
  const int xcd = lin & 7, j = lin >> 3;
  const int bh = xcd * 4 + (j >> 4);
  const int pr = j & 15;
  const int b = bh >> 4, h = bh & 15;
  const size_t tokbase = (size_t)b * 2048;
  const int qhi = 31 - pr;                // >= 16 always
  const int qt = (wv < 4) ? qhi : pr;
  const int ws = wv & 3;
  const int qg = qt * 64 + ws * 16 + lr;

  bf16x8 qf[2];
#pragma unroll
  for (int ks = 0; ks < 2; ++ks)
    qf[ks] = *(const bf16x8*)(qkv + (tokbase + qt * 64 + ws * 16 + lr) * 3072 +
                              h * 64 + ks * 32 + lg * 8);

  f32x4 o[4] = {};
  float m = -1e30f, lp = 0.f;

  const u16* kg_base = qkv + tokbase * 3072 + 1024 + h * 64;
  const u16* vg_base = Vt + (size_t)bh * 64 * 2048;

  const int soff = tid * 16;
  const int srow = soff >> 7;
  const int scol = (soff & 127) ^ ((srow & 7) << 4);
  auto stage = [&](int bsel, int kt2) {
    stage16((char*)&KV[bsel][0][0] + wv * 1024,
            kg_base + (size_t)(kt2 * 64 + srow) * 3072 + (scol >> 1));
    stage16((char*)&KV[bsel][1][0] + wv * 1024,
            vg_base + (size_t)srow * 2048 + kt2 * 64 + (scol >> 1));
  };

  auto compute = [&](int kt) {
    const char* Ks = (const char*)&KV[kt & 3][0][0];
    const char* Vs = (const char*)&KV[kt & 3][1][0];

    f32x4 s[4] = {};
#pragma unroll
    for (int ks = 0; ks < 2; ++ks)
#pragma unroll
      for (int nt = 0; nt < 4; ++nt) {
        const int row = nt * 16 + lr;
        const bf16x8 kf = *(const bf16x8*)(Ks + row * 128 +
                                           ((ks * 64 + lg * 16) ^ ((lr & 7) << 4)));
        s[nt] = __builtin_amdgcn_mfma_f32_16x16x32_bf16(kf, qf[ks], s[nt], 0, 0, 0);
      }

    float pmax = -1e30f;
    const bool diag = (kt == qt);
#pragma unroll
    for (int nt = 0; nt < 4; ++nt)
#pragma unroll
      for (int r = 0; r < 4; ++r) {
        float v = s[nt][r] * SCALE2;
        if (diag) {
          const int kg = kt * 64 + nt * 16 + lg * 4 + r;
          v = (kg <= qg) ? v : -1e30f;
        }
        s[nt][r] = v;
        pmax = fmaxf(pmax, v);
      }

    if (!__all(pmax - m <= DEFER_THR)) {
      float mx = fmaxf(pmax, __shfl_xor(pmax, 16));
      mx = fmaxf(mx, __shfl_xor(mx, 32));
      const float mn = fmaxf(m, mx);
      const float alpha = fexp2(m - mn);
      m = mn;
      lp *= alpha;
#pragma unroll
      for (int r = 0; r < 4; ++r) {
        const float ar = __shfl(alpha, lg * 4 + r);
#pragma unroll
        for (int dt = 0; dt < 4; ++dt) o[dt][r] *= ar;
      }
    }

#pragma unroll
    for (int nt = 0; nt < 4; ++nt) {
      const float p0 = fexp2(s[nt][0] - m), p1 = fexp2(s[nt][1] - m);
      const float p2 = fexp2(s[nt][2] - m), p3 = fexp2(s[nt][3] - m);
      lp += (p0 + p1) + (p2 + p3);
      uint2 w;
      w.x = (u32)f2bf(p0) | ((u32)f2bf(p1) << 16);
      w.y = (u32)f2bf(p2) | ((u32)f2bf(p3) << 16);
      *(uint2*)((char*)&Ps[wv][0] + lr * 128 + ((nt * 32 + lg * 8) ^ ((lr & 7) << 4))) = w;
    }

    bf16x8 pf[2];
#pragma unroll
    for (int ks = 0; ks < 2; ++ks) {
      const int jp = (ks * 4 + lg) ^ (lr & 7);
      pf[ks] = *(const bf16x8*)(&Ps[wv][0] + lr * 64 + jp * 8);
    }
#pragma unroll
    for (int ks = 0; ks < 2; ++ks)
#pragma unroll
      for (int dt = 0; dt < 4; ++dt) {
        const int row = dt * 16 + lr;
        const bf16x8 vf = *(const bf16x8*)(Vs + row * 128 +
                                           ((ks * 64 + lg * 16) ^ ((lr & 7) << 4)));
        o[dt] = __builtin_amdgcn_mfma_f32_16x16x32_bf16(pf[ks], vf, o[dt], 0, 0, 0);
      }
  };

  // prologue: stage tiles 0..3 (qhi >= 16, all exist); tiles 0,1 must land
  stage(0, 0); stage(1, 1); stage(2, 2); stage(3, 3);
  asm volatile("s_waitcnt vmcnt(4)\n\ts_barrier" ::: "memory");

  for (int kt = 0; kt <= qhi; kt += 2) {
    if (kt <= qt) compute(kt);
    if (kt + 1 <= qt) compute(kt + 1);
    // all waves' ds_reads of bufs kt,kt+1 are drained (MFMA deps); free them
    asm volatile("s_barrier" ::: "memory");
    if (kt + 4 <= qhi) stage((kt + 4) & 3, kt + 4);
    if (kt + 5 <= qhi) stage((kt + 5) & 3, kt + 5);
    if (kt + 2 <= qhi) {
      // join: kt+2,kt+3 must be landed; the 4 newest (kt+4,kt+5) may fly
      if (kt + 4 <= qhi)
        asm volatile("s_waitcnt vmcnt(4)\n\ts_barrier" ::: "memory");
      else
        asm volatile("s_waitcnt vmcnt(0)\n\ts_barrier" ::: "memory");
    }
  }

  float lsum = lp + __shfl_xor(lp, 16);
  lsum += __shfl_xor(lsum, 32);
#pragma unroll
  for (int r = 0; r < 4; ++r) {
    const float ld = __shfl(lsum, lg * 4 + r);
    const int tok = qt * 64 + ws * 16 + lg * 4 + r;
#pragma unroll
    for (int dt = 0; dt < 4; ++dt)
      attnout[(tokbase + tok) * 1024 + h * 64 + dt * 16 + lr] = f2bf(o[dt][r] / ld);
  }
}

// ---------------------------------------------------------------------------
extern "C" void kernel_launch(void* const* d_in, const int* in_sizes, int n_in,
                              void* d_out, int out_size, void* d_ws, size_t ws_size,
                              hipStream_t stream) {
  (void)in_sizes; (void)n_in; (void)ws_size;
  const float* x_in  = (const float*)d_in[0];
  const float* ln1_g = (const float*)d_in[2];
  const float* ln1_b = (const float*)d_in[3];
  const float* Wqkv  = (const float*)d_in[4];
  const float* Wout  = (const float*)d_in[5];
  const float* bout  = (const float*)d_in[6];
  const float* ln2_g = (const float*)d_in[7];
  const float* ln2_b = (const float*)d_in[8];
  const float* W1    = (const float*)d_in[9];
  const float* b1    = (const float*)d_in[10];
  const float* W2    = (const float*)d_in[11];
  const float* b2    = (const float*)d_in[12];
  float* x = (float*)d_out;   // residual stream lives in d_out

  char* ws = (char*)d_ws;
  size_t off = 0;
  auto alloc = [&](size_t bytes) -> void* {
    void* p = ws + off;
    off += (bytes + 255) & ~(size_t)255;
    return p;
  };
  u16* WqkvT = (u16*)alloc(4ull * 3072 * 1024 * 2);
  u16* WoutT = (u16*)alloc(4ull * 1024 * 1024 * 2);
  u16* W1T   = (u16*)alloc(4ull * 8192 * 1024 * 2);
  u16* W2T   = (u16*)alloc(4ull * 1024 * 4096 * 2);
  u16* y     = (u16*)alloc(4096ull * 1024 * 2);
  u16* qkvb  = (u16*)alloc(4096ull * 3072 * 2);
  u16* Vt    = (u16*)alloc(32ull * 64 * 2048 * 2);
  u16* attn  = (u16*)alloc(4096ull * 1024 * 2);
  u16* ff    = (u16*)alloc(4096ull * 4096 * 2);

  hipMemcpyAsync(x, x_in, (size_t)out_size * 4, hipMemcpyDeviceToDevice, stream);

  const dim3 tb(32, 8);
  wtrans_kernel<<<dim3(3072 / 32, 1024 / 32, 4), tb, 0, stream>>>(Wqkv, WqkvT, 1024, 3072, 0);
  wtrans_kernel<<<dim3(1024 / 32, 1024 / 32, 4), tb, 0, stream>>>(Wout, WoutT, 1024, 1024, 0);
  wtrans_kernel<<<dim3(8192 / 32, 1024 / 32, 4), tb, 0, stream>>>(W1, W1T, 1024, 8192, 1);
  wtrans_kernel<<<dim3(1024 / 32, 4096 / 32, 4), tb, 0, stream>>>(W2, W2T, 4096, 1024, 0);

  for (int l = 0; l < 4; ++l) {
    ln_kernel<<<4096, 256, 0, stream>>>(x, ln1_g + l * 1024, ln1_b + l * 1024, y);
    gemm4<0, 128, 128, 2, 2><<<dim3(3072 / 128, 4096 / 128), 256, 0, stream>>>(
        y, WqkvT + (size_t)l * 3072 * 1024, nullptr, nullptr, qkvb, 4096, 3072, 1024);
    vtrans_kernel<<<dim3(64, 2, 32), tb, 0, stream>>>(qkvb, Vt);
    attn_kernel<<<dim3(16, 32), 512, 0, stream>>>(qkvb, Vt, attn);
    gemm4<1, 128, 128, 2, 2><<<dim3(1024 / 128, 4096 / 128), 256, 0, stream>>>(
        attn, WoutT + (size_t)l * 1024 * 1024, x, bout + l * 1024, nullptr, 4096, 1024, 1024);
    ln_kernel<<<4096, 256, 0, stream>>>(x, ln2_g + l * 1024, ln2_b + l * 1024, y);
    gemm4<2, 256, 256, 2, 4><<<dim3(8192 / 256, 4096 / 256), 512, 0, stream>>>(
        y, W1T + (size_t)l * 8192 * 1024, nullptr, b1 + l * 8192, ff, 4096, 8192, 1024);
    gemm4<1, 128, 128, 2, 2><<<dim3(1024 / 128, 4096 / 128), 256, 0, stream>>>(
        ff, W2T + (size_t)l * 1024 * 4096, x, b2 + l * 1024, nullptr, 4096, 1024, 4096);
  }
}

// Round 17
// 1117.580 us; speedup vs baseline: 1.0142x; 1.0142x over previous
//
#include <hip/hip_runtime.h>

// ---------------------------------------------------------------------------
// Transformer (B=2, N=2048, D=1024, H=16, DH=64, DEPTH=4, FF=4, GEGLU, causal)
// R17: fuse the V-transpose into the QKV GEMM epilogue (EPI 3): V-region
// output blocks (n >= 2048, 128-aligned boundary) write packed ushort4
// directly into Vt[bh][64 d][2048 tok]; vtrans kernel dropped. Everything
// else frozen from R16 (gemm4 R11 config; attn quad-buffer counted barriers).
// ---------------------------------------------------------------------------

typedef float f32x4 __attribute__((ext_vector_type(4)));
typedef __bf16 bf16x8 __attribute__((ext_vector_type(8)));
typedef unsigned short u16;
typedef unsigned int u32;

#define SCALE2 0.18033688011112042f   // DH^-0.5 * log2(e)
#define LN_EPS 1e-3f
#define DEFER_THR 8.0f                // log2-domain: P bounded by 2^8

__device__ __forceinline__ float fexp2(float x) { return __builtin_amdgcn_exp2f(x); }

__device__ __forceinline__ u16 f2bf(float f) {
  u32 u = __float_as_uint(f);
  u += 0x7fffu + ((u >> 16) & 1u);   // round-to-nearest-even
  return (u16)(u >> 16);
}

// async global->LDS, 16B/lane; lds base wave-uniform (HW adds lane*16)
__device__ __forceinline__ void stage16(void* lds_wave_base, const void* gsrc) {
  __builtin_amdgcn_global_load_lds((__attribute__((address_space(1))) void*)gsrc,
                                   (__attribute__((address_space(3))) void*)lds_wave_base,
                                   16, 0, 0);
}

// ---------------------------------------------------------------------------
// Weight transpose + cast: W f32 [L][K][N] -> WT bf16 [L][N][K].
// permMode=1 (W1): rows permuted so 16 a-cols / 16 gate-cols alternate.
// ---------------------------------------------------------------------------
__global__ void wtrans_kernel(const float* __restrict__ W, u16* __restrict__ WT,
                              int K, int N, int permMode) {
  __shared__ float tile[32][33];
  const int n0 = blockIdx.x * 32, k0 = blockIdx.y * 32;
  const float* Wl = W + (size_t)blockIdx.z * K * N;
  u16* WTl = WT + (size_t)blockIdx.z * K * N;
  const int tx = threadIdx.x, ty = threadIdx.y;
#pragma unroll
  for (int i = 0; i < 4; ++i)
    tile[ty + i * 8][tx] = Wl[(size_t)(k0 + ty + i * 8) * N + n0 + tx];
  __syncthreads();
#pragma unroll
  for (int i = 0; i < 4; ++i) {
    const int n = n0 + ty + i * 8;
    int orow;
    if (permMode) {
      orow = (n < 4096) ? (((n >> 4) << 5) + (n & 15))
                        : ((((n - 4096) >> 4) << 5) + 16 + (n & 15));
    } else {
      orow = n;
    }
    WTl[(size_t)orow * K + k0 + tx] = f2bf(tile[tx][ty + i * 8]);
  }
}

// ---------------------------------------------------------------------------
// LayerNorm: x f32 [4096][1024] -> y bf16
// ---------------------------------------------------------------------------
__global__ __launch_bounds__(256, 4)
void ln_kernel(const float* __restrict__ x, const float* __restrict__ g,
               const float* __restrict__ b, u16* __restrict__ y) {
  const int row = blockIdx.x, tid = threadIdx.x;
  const float4 v = ((const float4*)(x + (size_t)row * 1024))[tid];
  float s = v.x + v.y + v.z + v.w;
  float s2 = v.x * v.x + v.y * v.y + v.z * v.z + v.w * v.w;
#pragma unroll
  for (int off = 32; off > 0; off >>= 1) {
    s += __shfl_down(s, off);
    s2 += __shfl_down(s2, off);
  }
  __shared__ float ps[8];
  __shared__ float stats[2];
  const int wv = tid >> 6, lane = tid & 63;
  if (lane == 0) { ps[wv] = s; ps[wv + 4] = s2; }
  __syncthreads();
  if (tid == 0) {
    const float S = ps[0] + ps[1] + ps[2] + ps[3];
    const float S2 = ps[4] + ps[5] + ps[6] + ps[7];
    const float mu = S * (1.0f / 1024.0f);
    const float var = S2 * (1.0f / 1024.0f) - mu * mu;
    stats[0] = mu;
    stats[1] = rsqrtf(var + LN_EPS);
  }
  __syncthreads();
  const float mu = stats[0], rs = stats[1];
  const float4 gg = ((const float4*)g)[tid];
  const float4 bb = ((const float4*)b)[tid];
  ushort4 ov;
  ov.x = f2bf((v.x - mu) * rs * gg.x + bb.x);
  ov.y = f2bf((v.y - mu) * rs * gg.y + bb.y);
  ov.z = f2bf((v.z - mu) * rs * gg.z + bb.z);
  ov.w = f2bf((v.w - mu) * rs * gg.w + bb.w);
  ((ushort4*)(y + (size_t)row * 1024))[tid] = ov;
}

// ---------------------------------------------------------------------------
// gemm4: BK=64 cross-tile ks-split pipeline, 2 LDS buffers, XOR-swizzled
// 128B rows, counted vmcnt joins, setprio MFMA clusters.
// EPI 0: out bf16 = acc
// EPI 1: resid f32 += acc + bias
// EPI 2: GEGLU -> out bf16 [M][4096]
// EPI 3: QKV: n<2048 -> out (qkvb Q/K region); n>=2048 -> packed ushort4
//        direct into Vt[bh][64 d][2048 tok] (vtrans fused away).
// ---------------------------------------------------------------------------
template <int EPI, int BM, int BN, int WM, int WN>
__global__ __launch_bounds__(WM * WN * 64, 2)
void gemm4(const u16* __restrict__ A, const u16* __restrict__ B,
           float* __restrict__ resid, const float* __restrict__ bias,
           u16* __restrict__ out, u16* __restrict__ vt, int M, int N, int K) {
  constexpr int NTHR = WM * WN * 64;
  constexpr int MT = BM / WM / 16;
  constexpr int NT = BN / WN / 16;
  __shared__ __align__(16) u16 lds[2][(BM + BN) * 64];

  const int tid = threadIdx.x;
  const int wv = tid >> 6, lane = tid & 63;
  const int lr = lane & 15, lg = lane >> 4;
  const int wmi = wv / WN, wni = wv % WN;
  const int RB0 = wmi * (BM / WM), CB0 = wni * (BN / WN);

  const int nwg = (int)(gridDim.x * gridDim.y);
  int id = (int)(blockIdx.y * gridDim.x + blockIdx.x);
  id = (id & 7) * (nwg >> 3) + (id >> 3);
  const int m0 = (id / (int)gridDim.x) * BM, n0 = (id % (int)gridDim.x) * BN;

  auto stage = [&](int bsel, int k0) {
    u16* dstA = &lds[bsel][0];
    u16* dstB = &lds[bsel][BM * 64];
#pragma unroll
    for (int rnd = 0; rnd < (BM * 128) / (NTHR * 16); ++rnd) {
      const int base = rnd * (NTHR * 16) + wv * 1024;
      const int off = base + lane * 16;
      const int row = off >> 7;
      const int k2 = (off & 127) ^ ((row & 7) << 4);
      stage16((char*)dstA + base, A + (size_t)(m0 + row) * K + k0 + (k2 >> 1));
    }
#pragma unroll
    for (int rnd = 0; rnd < (BN * 128) / (NTHR * 16); ++rnd) {
      const int base = rnd * (NTHR * 16) + wv * 1024;
      const int off = base + lane * 16;
      const int row = off >> 7;
      const int k2 = (off & 127) ^ ((row & 7) << 4);
      stage16((char*)dstB + base, B + (size_t)(n0 + row) * K + k0 + (k2 >> 1));
    }
  };

  f32x4 acc[MT][NT] = {};
  bf16x8 afr0[MT], bfr0[NT], afr1[MT], bfr1[NT];

  auto rd = [&](int bsel, int ks, bf16x8 (&af)[MT], bf16x8 (&bf)[NT]) {
    const char* As = (const char*)&lds[bsel][0];
    const char* Bs = (const char*)&lds[bsel][BM * 64];
#pragma unroll
    for (int mt = 0; mt < MT; ++mt) {
      const int row = RB0 + mt * 16 + lr;
      af[mt] = *(const bf16x8*)(As + row * 128 + ((ks * 64 + lg * 16) ^ ((lr & 7) << 4)));
    }
#pragma unroll
    for (int nt = 0; nt < NT; ++nt) {
      const int row = CB0 + nt * 16 + lr;
      bf[nt] = *(const bf16x8*)(Bs + row * 128 + ((ks * 64 + lg * 16) ^ ((lr & 7) << 4)));
    }
  };

  const int nT = K >> 6;
  stage(0, 0);
  stage(1, 64);
  asm volatile("s_waitcnt vmcnt(8)\n\ts_barrier" ::: "memory");
  rd(0, 0, afr0, bfr0);
  __builtin_amdgcn_sched_barrier(0);

  for (int t = 0; t < nT; ++t) {
    const int c = t & 1;
    rd(c, 1, afr1, bfr1);
    __builtin_amdgcn_sched_barrier(0);
    __builtin_amdgcn_s_setprio(1);
#pragma unroll
    for (int mt = 0; mt < MT; ++mt)
#pragma unroll
      for (int nt = 0; nt < NT; ++nt)
        acc[mt][nt] = __builtin_amdgcn_mfma_f32_16x16x32_bf16(
            afr0[mt], bfr0[nt], acc[mt][nt], 0, 0, 0);
    __builtin_amdgcn_s_setprio(0);
    __builtin_amdgcn_sched_barrier(0);
    asm volatile("s_waitcnt lgkmcnt(0)\n\ts_barrier" ::: "memory");
    __builtin_amdgcn_sched_barrier(0);
    if (t + 2 < nT) stage(c, (t + 2) * 64);
    if (t + 1 < nT) {
      if (t + 2 < nT)
        asm volatile("s_waitcnt vmcnt(8)\n\ts_barrier" ::: "memory");
      else
        asm volatile("s_waitcnt vmcnt(0)\n\ts_barrier" ::: "memory");
      rd(c ^ 1, 0, afr0, bfr0);
      __builtin_amdgcn_sched_barrier(0);
    }
    __builtin_amdgcn_s_setprio(1);
#pragma unroll
    for (int mt = 0; mt < MT; ++mt)
#pragma unroll
      for (int nt = 0; nt < NT; ++nt)
        acc[mt][nt] = __builtin_amdgcn_mfma_f32_16x16x32_bf16(
            afr1[mt], bfr1[nt], acc[mt][nt], 0, 0, 0);
    __builtin_amdgcn_s_setprio(0);
  }

  // C/D: m = m0 + RB0 + mt*16 + lg*4 + r ; n = n0 + CB0 + nt*16 + lr
  if (EPI == 0) {
#pragma unroll
    for (int mt = 0; mt < MT; ++mt)
#pragma unroll
      for (int nt = 0; nt < NT; ++nt) {
        const int n = n0 + CB0 + nt * 16 + lr;
#pragma unroll
        for (int r = 0; r < 4; ++r) {
          const int m = m0 + RB0 + mt * 16 + lg * 4 + r;
          out[(size_t)m * N + n] = f2bf(acc[mt][nt][r]);
        }
      }
  } else if (EPI == 1) {
    float bs[NT];
#pragma unroll
    for (int nt = 0; nt < NT; ++nt) bs[nt] = bias[n0 + CB0 + nt * 16 + lr];
#pragma unroll
    for (int mt = 0; mt < MT; ++mt)
#pragma unroll
      for (int nt = 0; nt < NT; ++nt) {
        const int n = n0 + CB0 + nt * 16 + lr;
#pragma unroll
        for (int r = 0; r < 4; ++r) {
          const int m = m0 + RB0 + mt * 16 + lg * 4 + r;
          resid[(size_t)m * N + n] += acc[mt][nt][r] + bs[nt];
        }
      }
  } else if (EPI == 2) {
#pragma unroll
    for (int pt = 0; pt < NT / 2; ++pt) {
      const int colA = ((n0 + CB0 + pt * 32) >> 5) * 16 + lr;
      const float ba = bias[colA];
      const float bg = bias[4096 + colA];
#pragma unroll
      for (int mt = 0; mt < MT; ++mt)
#pragma unroll
        for (int r = 0; r < 4; ++r) {
          const int m = m0 + RB0 + mt * 16 + lg * 4 + r;
          const float a = acc[mt][2 * pt][r] + ba;
          const float g = acc[mt][2 * pt + 1][r] + bg;
          const float gl = 0.5f * g * (1.0f + erff(g * 0.70710678118654752f));
          out[(size_t)m * 4096 + colA] = f2bf(a * gl);
        }
    }
  } else {   // EPI 3: QKV with fused V-transpose
    if (n0 + CB0 < 2048) {
      // Q/K region -> qkvb as usual
#pragma unroll
      for (int mt = 0; mt < MT; ++mt)
#pragma unroll
        for (int nt = 0; nt < NT; ++nt) {
          const int n = n0 + CB0 + nt * 16 + lr;
#pragma unroll
          for (int r = 0; r < 4; ++r) {
            const int m = m0 + RB0 + mt * 16 + lg * 4 + r;
            out[(size_t)m * N + n] = f2bf(acc[mt][nt][r]);
          }
        }
    } else {
      // V region -> Vt[bh][64 d][2048 tok]; block m-span within one batch
      const int bidx = m0 >> 11;                       // batch of this block
      const int tokb = (m0 & 2047) + RB0 + lg * 4;     // + mt*16 later
#pragma unroll
      for (int mt = 0; mt < MT; ++mt)
#pragma unroll
        for (int nt = 0; nt < NT; ++nt) {
          const int n = n0 + CB0 + nt * 16 + lr;       // 2048..3071
          const int hv = (n - 2048) >> 6;              // head
          const int d = (n - 2048) & 63;               // dim within head
          ushort4 w;
          w.x = f2bf(acc[mt][nt][0]);
          w.y = f2bf(acc[mt][nt][1]);
          w.z = f2bf(acc[mt][nt][2]);
          w.w = f2bf(acc[mt][nt][3]);
          *(ushort4*)(vt + ((size_t)(bidx * 16 + hv) * 64 + d) * 2048 +
                      tokb + mt * 16) = w;
        }
    }
  }
}

// ---------------------------------------------------------------------------
// Causal flash attention (R16, unchanged): quad-buffered K/V, counted
// 2-K-tile barrier pairs, 8-wave paired blocks, XCD-pinned bh, swapped QK^T,
// defer-max, per-lane partial l.
// ---------------------------------------------------------------------------
__global__ __launch_bounds__(512, 4)
void attn_kernel(const u16* __restrict__ qkv, const u16* __restrict__ Vt,
                 u16* __restrict__ attnout) {
  __shared__ __align__(16) u16 KV[4][2][64 * 64];
  __shared__ __align__(16) u16 Ps[8][16 * 64];

  const int tid = threadIdx.x;
  const int wv = tid >> 6, lane = tid & 63;
  const int lr = lane & 15, lg = lane >> 4;
  const int lin = (int)(blockIdx.y * gridDim.x + blockIdx.x);
  const int xcd = lin & 7, j = lin >> 3;
  const int bh = xcd * 4 + (j >> 4);
  const int pr = j & 15;
  const int b = bh >> 4, h = bh & 15;
  const size_t tokbase = (size_t)b * 2048;
  const int qhi = 31 - pr;
  const int qt = (wv < 4) ? qhi : pr;
  const int ws = wv & 3;
  const int qg = qt * 64 + ws * 16 + lr;

  bf16x8 qf[2];
#pragma unroll
  for (int ks = 0; ks < 2; ++ks)
    qf[ks] = *(const bf16x8*)(qkv + (tokbase + qt * 64 + ws * 16 + lr) * 3072 +
                              h * 64 + ks * 32 + lg * 8);

  f32x4 o[4] = {};
  float m = -1e30f, lp = 0.f;

  const u16* kg_base = qkv + tokbase * 3072 + 1024 + h * 64;
  const u16* vg_base = Vt + (size_t)bh * 64 * 2048;

  const int soff = tid * 16;
  const int srow = soff >> 7;
  const int scol = (soff & 127) ^ ((srow & 7) << 4);
  auto stage = [&](int bsel, int kt2) {
    stage16((char*)&KV[bsel][0][0] + wv * 1024,
            kg_base + (size_t)(kt2 * 64 + srow) * 3072 + (scol >> 1));
    stage16((char*)&KV[bsel][1][0] + wv * 1024,
            vg_base + (size_t)srow * 2048 + kt2 * 64 + (scol >> 1));
  };

  auto compute = [&](int kt) {
    const char* Ks = (const char*)&KV[kt & 3][0][0];
    const char* Vs = (const char*)&KV[kt & 3][1][0];

    f32x4 s[4] = {};
#pragma unroll
    for (int ks = 0; ks < 2; ++ks)
#pragma unroll
      for (int nt = 0; nt < 4; ++nt) {
        const int row = nt * 16 + lr;
        const bf16x8 kf = *(const bf16x8*)(Ks + row * 128 +
                                           ((ks * 64 + lg * 16) ^ ((lr & 7) << 4)));
        s[nt] = __builtin_amdgcn_mfma_f32_16x16x32_bf16(kf, qf[ks], s[nt], 0, 0, 0);
      }

    float pmax = -1e30f;
    const bool diag = (kt == qt);
#pragma unroll
    for (int nt = 0; nt < 4; ++nt)
#pragma unroll
      for (int r = 0; r < 4; ++r) {
        float v = s[nt][r] * SCALE2;
        if (diag) {
          const int kg = kt * 64 + nt * 16 + lg * 4 + r;
          v = (kg <= qg) ? v : -1e30f;
        }
        s[nt][r] = v;
        pmax = fmaxf(pmax, v);
      }

    if (!__all(pmax - m <= DEFER_THR)) {
      float mx = fmaxf(pmax, __shfl_xor(pmax, 16));
      mx = fmaxf(mx, __shfl_xor(mx, 32));
      const float mn = fmaxf(m, mx);
      const float alpha = fexp2(m - mn);
      m = mn;
      lp *= alpha;
#pragma unroll
      for (int r = 0; r < 4; ++r) {
        const float ar = __shfl(alpha, lg * 4 + r);
#pragma unroll
        for (int dt = 0; dt < 4; ++dt) o[dt][r] *= ar;
      }
    }

#pragma unroll
    for (int nt = 0; nt < 4; ++nt) {
      const float p0 = fexp2(s[nt][0] - m), p1 = fexp2(s[nt][1] - m);
      const float p2 = fexp2(s[nt][2] - m), p3 = fexp2(s[nt][3] - m);
      lp += (p0 + p1) + (p2 + p3);
      uint2 w;
      w.x = (u32)f2bf(p0) | ((u32)f2bf(p1) << 16);
      w.y = (u32)f2bf(p2) | ((u32)f2bf(p3) << 16);
      *(uint2*)((char*)&Ps[wv][0] + lr * 128 + ((nt * 32 + lg * 8) ^ ((lr & 7) << 4))) = w;
    }

    bf16x8 pf[2];
#pragma unroll
    for (int ks = 0; ks < 2; ++ks) {
      const int jp = (ks * 4 + lg) ^ (lr & 7);
      pf[ks] = *(const bf16x8*)(&Ps[wv][0] + lr * 64 + jp * 8);
    }
#pragma unroll
    for (int ks = 0; ks < 2; ++ks)
#pragma unroll
      for (int dt = 0; dt < 4; ++dt) {
        const int row = dt * 16 + lr;
        const bf16x8 vf = *(const bf16x8*)(Vs + row * 128 +
                                           ((ks * 64 + lg * 16) ^ ((lr & 7) << 4)));
        o[dt] = __builtin_amdgcn_mfma_f32_16x16x32_bf16(pf[ks], vf, o[dt], 0, 0, 0);
      }
  };

  stage(0, 0); stage(1, 1); stage(2, 2); stage(3, 3);
  asm volatile("s_waitcnt vmcnt(4)\n\ts_barrier" ::: "memory");

  for (int kt = 0; kt <= qhi; kt += 2) {
    if (kt <= qt) compute(kt);
    if (kt + 1 <= qt) compute(kt + 1);
    asm volatile("s_barrier" ::: "memory");
    if (kt + 4 <= qhi) stage((kt + 4) & 3, kt + 4);
    if (kt + 5 <= qhi) stage((kt + 5) & 3, kt + 5);
    if (kt + 2 <= qhi) {
      if (kt + 4 <= qhi)
        asm volatile("s_waitcnt vmcnt(4)\n\ts_barrier" ::: "memory");
      else
        asm volatile("s_waitcnt vmcnt(0)\n\ts_barrier" ::: "memory");
    }
  }

  float lsum = lp + __shfl_xor(lp, 16);
  lsum += __shfl_xor(lsum, 32);
#pragma unroll
  for (int r = 0; r < 4; ++r) {
    const float ld = __shfl(lsum, lg * 4 + r);
    const int tok = qt * 64 + ws * 16 + lg * 4 + r;
#pragma unroll
    for (int dt = 0; dt < 4; ++dt)
      attnout[(tokbase + tok) * 1024 + h * 64 + dt * 16 + lr] = f2bf(o[dt][r] / ld);
  }
}

// ---------------------------------------------------------------------------
extern "C" void kernel_launch(void* const* d_in, const int* in_sizes, int n_in,
                              void* d_out, int out_size, void* d_ws, size_t ws_size,
                              hipStream_t stream) {
  (void)in_sizes; (void)n_in; (void)ws_size;
  const float* x_in  = (const float*)d_in[0];
  const float* ln1_g = (const float*)d_in[2];
  const float* ln1_b = (const float*)d_in[3];
  const float* Wqkv  = (const float*)d_in[4];
  const float* Wout  = (const float*)d_in[5];
  const float* bout  = (const float*)d_in[6];
  const float* ln2_g = (const float*)d_in[7];
  const float* ln2_b = (const float*)d_in[8];
  const float* W1    = (const float*)d_in[9];
  const float* b1    = (const float*)d_in[10];
  const float* W2    = (const float*)d_in[11];
  const float* b2    = (const float*)d_in[12];
  float* x = (float*)d_out;   // residual stream lives in d_out

  char* ws = (char*)d_ws;
  size_t off = 0;
  auto alloc = [&](size_t bytes) -> void* {
    void* p = ws + off;
    off += (bytes + 255) & ~(size_t)255;
    return p;
  };
  u16* WqkvT = (u16*)alloc(4ull * 3072 * 1024 * 2);
  u16* WoutT = (u16*)alloc(4ull * 1024 * 1024 * 2);
  u16* W1T   = (u16*)alloc(4ull * 8192 * 1024 * 2);
  u16* W2T   = (u16*)alloc(4ull * 1024 * 4096 * 2);
  u16* y     = (u16*)alloc(4096ull * 1024 * 2);
  u16* qkvb  = (u16*)alloc(4096ull * 3072 * 2);
  u16* Vt    = (u16*)alloc(32ull * 64 * 2048 * 2);
  u16* attn  = (u16*)alloc(4096ull * 1024 * 2);
  u16* ff    = (u16*)alloc(4096ull * 4096 * 2);

  hipMemcpyAsync(x, x_in, (size_t)out_size * 4, hipMemcpyDeviceToDevice, stream);

  const dim3 tb(32, 8);
  wtrans_kernel<<<dim3(3072 / 32, 1024 / 32, 4), tb, 0, stream>>>(Wqkv, WqkvT, 1024, 3072, 0);
  wtrans_kernel<<<dim3(1024 / 32, 1024 / 32, 4), tb, 0, stream>>>(Wout, WoutT, 1024, 1024, 0);
  wtrans_kernel<<<dim3(8192 / 32, 1024 / 32, 4), tb, 0, stream>>>(W1, W1T, 1024, 8192, 1);
  wtrans_kernel<<<dim3(1024 / 32, 4096 / 32, 4), tb, 0, stream>>>(W2, W2T, 4096, 1024, 0);

  for (int l = 0; l < 4; ++l) {
    ln_kernel<<<4096, 256, 0, stream>>>(x, ln1_g + l * 1024, ln1_b + l * 1024, y);
    gemm4<3, 128, 128, 2, 2><<<dim3(3072 / 128, 4096 / 128), 256, 0, stream>>>(
        y, WqkvT + (size_t)l * 3072 * 1024, nullptr, nullptr, qkvb, Vt, 4096, 3072, 1024);
    attn_kernel<<<dim3(16, 32), 512, 0, stream>>>(qkvb, Vt, attn);
    gemm4<1, 128, 128, 2, 2><<<dim3(1024 / 128, 4096 / 128), 256, 0, stream>>>(
        attn, WoutT + (size_t)l * 1024 * 1024, x, bout + l * 1024, nullptr, nullptr,
        4096, 1024, 1024);
    ln_kernel<<<4096, 256, 0, stream>>>(x, ln2_g + l * 1024, ln2_b + l * 1024, y);
    gemm4<2, 256, 256, 2, 4><<<dim3(8192 / 256, 4096 / 256), 512, 0, stream>>>(
        y, W1T + (size_t)l * 8192 * 1024, nullptr, b1 + l * 8192, ff, nullptr,
        4096, 8192, 1024);
    gemm4<1, 128, 128, 2, 2><<<dim3(1024 / 128, 4096 / 128), 256, 0, stream>>>(
        ff, W2T + (size_t)l * 1024 * 4096, x, b2 + l * 1024, nullptr, nullptr,
        4096, 1024, 4096);
  }
}